// Round 1
// 3940.553 us; speedup vs baseline: 1.3108x; 1.3108x over previous
//
#include <hip/hip_runtime.h>
#include <hip/hip_bf16.h>
#include <math.h>

#define N_NODES 100000
#define D_IN 256
#define D_OUT 64
#define N_HEADS 4
#define P_TOTAL 5
#define NEDGE 3200000

__device__ __forceinline__ unsigned short f2bf(float f) {
    unsigned u = __float_as_uint(f);
    unsigned r = (u + 0x7FFFu + ((u >> 16) & 1u)) >> 16;
    return (unsigned short)r;
}

// ---------------------------------------------------------------------------
__global__ void zero_kernel(int* __restrict__ p, int n) {
    int i = blockIdx.x * blockDim.x + threadIdx.x;
    if (i < n) p[i] = 0;
}

// ---------------------------------------------------------------------------
// h = (shrink[m,i] @ x).T  -> Hb bf16 [m][n][256]  (ch = i*64+d, node-major)
// Fused epilogue: A0[pi][n] = h . att0[pi], A1 likewise, from fp32 accs.
// blockIdx.y == head i (c0 = i*64), blockIdx.z == m.
// ---------------------------------------------------------------------------
__global__ __launch_bounds__(256)
void gemm_h(const float* __restrict__ x, const float* __restrict__ W,
            const float* __restrict__ att0, const float* __restrict__ att1,
            unsigned short* __restrict__ Hb,
            float* __restrict__ A0, float* __restrict__ A1) {
    const int m  = blockIdx.z;
    const int i  = blockIdx.y;        // head
    const int c0 = i * 64;
    const int n0 = blockIdx.x * 64;
    __shared__ float xs[32][68];
    __shared__ float ws[32][68];
    const int t  = threadIdx.x;
    const int c4 = (t & 15) * 4;
    const int n4 = (t >> 4) * 4;
    float acc[4][4];
#pragma unroll
    for (int a = 0; a < 4; ++a)
#pragma unroll
        for (int b = 0; b < 4; ++b) acc[a][b] = 0.f;

    for (int k0 = 0; k0 < 256; k0 += 32) {
#pragma unroll
        for (int it = 0; it < 8; ++it) {
            int idx = it * 256 + t;
            int kk = idx >> 6;
            int nn = idx & 63;
            int gn = n0 + nn;
            xs[kk][nn] = (gn < N_NODES) ? x[(size_t)(k0 + kk) * N_NODES + gn] : 0.f;
        }
#pragma unroll
        for (int it = 0; it < 8; ++it) {
            int idx = it * 256 + t;
            int cc = idx >> 5;
            int kk = idx & 31;
            ws[kk][cc] = W[((size_t)(m * 256 + c0 + cc)) * 256 + (k0 + kk)];
        }
        __syncthreads();
#pragma unroll
        for (int k = 0; k < 32; ++k) {
            float4 xv = *(const float4*)&xs[k][n4];
            float4 wv = *(const float4*)&ws[k][c4];
            float xa[4] = {xv.x, xv.y, xv.z, xv.w};
            float wa[4] = {wv.x, wv.y, wv.z, wv.w};
#pragma unroll
            for (int a = 0; a < 4; ++a)
#pragma unroll
                for (int b = 0; b < 4; ++b) acc[a][b] += xa[a] * wa[b];
        }
        __syncthreads();
    }
    // bf16 H writeback
#pragma unroll
    for (int a = 0; a < 4; ++a) {
        int gn = n0 + n4 + a;
        if (gn < N_NODES) {
            ushort4 s4;
            s4.x = f2bf(acc[a][0]); s4.y = f2bf(acc[a][1]);
            s4.z = f2bf(acc[a][2]); s4.w = f2bf(acc[a][3]);
            *(ushort4*)&Hb[((size_t)m * N_NODES + gn) * 256 + c0 + c4] = s4;
        }
    }
    // fused attention scalars (fp32 precision)
    const int p0 = m ? 2 : 0;
    const int np = m ? 3 : 2;
    for (int pk = 0; pk < np; ++pk) {
        const int pi = (p0 + pk) * 4 + i;
        float a0v[4], a1v[4];
#pragma unroll
        for (int b = 0; b < 4; ++b) {
            a0v[b] = att0[pi * 64 + c4 + b];
            a1v[b] = att1[pi * 64 + c4 + b];
        }
#pragma unroll
        for (int a = 0; a < 4; ++a) {
            float s0 = 0.f, s1 = 0.f;
#pragma unroll
            for (int b = 0; b < 4; ++b) {
                s0 += acc[a][b] * a0v[b];
                s1 += acc[a][b] * a1v[b];
            }
#pragma unroll
            for (int off = 1; off < 16; off <<= 1) {
                s0 += __shfl_xor(s0, off);
                s1 += __shfl_xor(s1, off);
            }
            int gn = n0 + n4 + a;
            if ((t & 15) == 0 && gn < N_NODES) {
                A0[(size_t)pi * N_NODES + gn] = s0;
                A1[(size_t)pi * N_NODES + gn] = s1;
            }
        }
    }
}

// ---------------------------------------------------------------------------
// CSR build: histogram -> 3-phase exclusive scan -> scatter packed (c,v) u32
// ---------------------------------------------------------------------------
__global__ __launch_bounds__(256)
void hist_kernel(const int* __restrict__ rows, int* __restrict__ counts) {
    const int p = blockIdx.y;
    const int e = blockIdx.x * 256 + threadIdx.x;
    int r = rows[(size_t)p * NEDGE + e];
    atomicAdd(&counts[p * N_NODES + r], 1);
}

__global__ __launch_bounds__(1024)
void scan1(const int* __restrict__ counts, int* __restrict__ rowstart,
           int* __restrict__ blocksum) {
    __shared__ int sh[1024];
    const int p = blockIdx.y, b = blockIdx.x, t = threadIdx.x;
    const int i = b * 1024 + t;
    int v = (i < N_NODES) ? counts[p * N_NODES + i] : 0;
    sh[t] = v;
    __syncthreads();
    for (int off = 1; off < 1024; off <<= 1) {
        int y = (t >= off) ? sh[t - off] : 0;
        __syncthreads();
        sh[t] += y;
        __syncthreads();
    }
    if (i < N_NODES) rowstart[p * (N_NODES + 1) + i] = sh[t] - v;
    if (t == 1023) blocksum[p * 128 + b] = sh[t];
}

__global__ __launch_bounds__(128)
void scan2(int* __restrict__ blocksum, int* __restrict__ rowstart, int nb) {
    __shared__ int sh[128];
    const int p = blockIdx.x, t = threadIdx.x;
    int v = (t < nb) ? blocksum[p * 128 + t] : 0;
    sh[t] = v;
    __syncthreads();
    for (int off = 1; off < 128; off <<= 1) {
        int y = (t >= off) ? sh[t - off] : 0;
        __syncthreads();
        sh[t] += y;
        __syncthreads();
    }
    blocksum[p * 128 + t] = sh[t] - v;
    if (t == 0) rowstart[p * (N_NODES + 1) + N_NODES] = NEDGE;
}

__global__ __launch_bounds__(1024)
void scan3(int* __restrict__ rowstart, const int* __restrict__ blocksum) {
    const int p = blockIdx.y, b = blockIdx.x, t = threadIdx.x;
    const int i = b * 1024 + t;
    if (i < N_NODES) rowstart[p * (N_NODES + 1) + i] += blocksum[p * 128 + b];
}

__global__ __launch_bounds__(256)
void scatter_kernel(const int* __restrict__ rows, const int* __restrict__ cols,
                    const float* __restrict__ vals, const int* __restrict__ rowstart,
                    int* __restrict__ cursor, unsigned* __restrict__ cv) {
    const int p = blockIdx.y;
    const size_t base = (size_t)p * NEDGE;
    const size_t e = (size_t)blockIdx.x * 256 + threadIdx.x;
    int r = rows[base + e];
    int c = cols[base + e];
    float v = vals[base + e];
    int q = (int)(v * 32768.0f + 0.5f);
    if (q > 32767) q = 32767;
    unsigned cu = ((unsigned)c << 15) | (unsigned)q;
    int pos = rowstart[p * (N_NODES + 1) + r] + atomicAdd(&cursor[p * N_NODES + r], 1);
    cv[base + pos] = cu;
}

// ---------------------------------------------------------------------------
// Main pass: block = 4 waves (one head each); wave splits into two halves,
// each half processes alternate edges. Edge loop is BATCHED x4 (8 edges in
// flight per wave) with predicated loads so 4 cv-loads then 8 gathers issue
// back-to-back -- this is the MLP fix for the latency-bound gather chain.
// Lane l (0..31) of each half holds channels d = 2l, 2l+1 (bf16x2 gather).
// Softmax denominator division deferred per (row, position); combine halves
// with one shfl_xor(32) per position.
// ---------------------------------------------------------------------------
__global__ __launch_bounds__(256)
void row_pass(const unsigned short* __restrict__ Hb, const float* __restrict__ A0,
              const float* __restrict__ A1, const int* __restrict__ rowstart,
              const unsigned* __restrict__ cv, float* __restrict__ out) {
    const int m    = blockIdx.y;
    const int r0   = blockIdx.x * 16;
    const int i    = threadIdx.x >> 6;   // head
    const int lane = threadIdx.x & 63;
    const int half = lane >> 5;
    const int l    = lane & 31;
    __shared__ float tile[4][16][66];
    const int p0 = m ? 2 : 0;
    const int np = m ? 3 : 2;
    const unsigned* Hm32 = (const unsigned*)(Hb + (size_t)m * N_NODES * 256);
    const int hoff = i * 32 + l;   // u32 offset within a 128-u32 H row

    for (int rt = 0; rt < 16; ++rt) {
        const int r = r0 + rt;
        float acc0 = 0.f, acc1 = 0.f;
        for (int pk = 0; pk < np; ++pk) {
            const int p  = p0 + pk;
            const int pi = p * 4 + i;
            const int* rs = rowstart + p * (N_NODES + 1);
            const int e0 = rs[r], e1 = rs[r + 1];
            if (e1 > e0) {
                const float a1r = A1[(size_t)pi * N_NODES + r];
                const float* A0p = A0 + (size_t)pi * N_NODES;
                const unsigned* cvp = cv + (size_t)p * NEDGE;
                float den = 0.f, num0 = 0.f, num1 = 0.f;
                // batched-by-4 edge loop: this half owns e0+half, e0+half+2, ...
                for (int e = e0 + half; e < e1; e += 8) {
                    unsigned cu[4];
                    unsigned hu[4];
                    float    a0v[4];
                    unsigned coff[4];
                    bool     act[4];
#pragma unroll
                    for (int q = 0; q < 4; ++q) {
                        int ee = e + 2 * q;
                        act[q] = ee < e1;
                        cu[q] = cvp[act[q] ? ee : e0];   // safe addr, masked later
                    }
#pragma unroll
                    for (int q = 0; q < 4; ++q) {
                        unsigned c = cu[q] >> 15;
                        coff[q] = c * 128u + (unsigned)hoff;
                        a0v[q] = A0p[c];
                    }
#pragma unroll
                    for (int q = 0; q < 4; ++q) hu[q] = Hm32[coff[q]];
#pragma unroll
                    for (int q = 0; q < 4; ++q) {
                        float v = (float)(cu[q] & 32767u) * (1.0f / 32768.0f);
                        float w = act[q] ? __expf(v * (a0v[q] + a1r)) : 0.f;
                        float h0 = __uint_as_float(hu[q] << 16);
                        float h1 = __uint_as_float(hu[q] & 0xFFFF0000u);
                        den  += w;
                        num0 += w * h0;
                        num1 += w * h1;
                    }
                }
                float dt  = den  + __shfl_xor(den, 32);
                float n0t = num0 + __shfl_xor(num0, 32);
                float n1t = num1 + __shfl_xor(num1, 32);
                acc0 += n0t / dt;
                acc1 += n1t / dt;
            }
        }
        acc0 = acc0 > 0.f ? acc0 : __expf(acc0) - 1.f;  // ELU
        acc1 = acc1 > 0.f ? acc1 : __expf(acc1) - 1.f;
        if (half == 0)
            *(float2*)&tile[i][rt][2 * l] = make_float2(acc0, acc1);
    }
    __syncthreads();
    {
        const int ch = threadIdx.x;
        const int ii = ch >> 6, d = ch & 63;
        float* dst = out + ((size_t)m * 256 + ch) * N_NODES + r0;
#pragma unroll
        for (int q = 0; q < 4; ++q) {
            float4 v4 = make_float4(tile[ii][q * 4 + 0][d], tile[ii][q * 4 + 1][d],
                                    tile[ii][q * 4 + 2][d], tile[ii][q * 4 + 3][d]);
            *(float4*)(dst + q * 4) = v4;
        }
    }
}

// ---------------------------------------------------------------------------
extern "C" void kernel_launch(void* const* d_in, const int* in_sizes, int n_in,
                              void* d_out, int out_size, void* d_ws, size_t ws_size,
                              hipStream_t stream) {
    const float* x    = (const float*)d_in[0];
    const float* W    = (const float*)d_in[1];
    const float* att0 = (const float*)d_in[2];
    const float* att1 = (const float*)d_in[3];
    const int*   erows = (const int*)d_in[4];
    const int*   ecols = (const int*)d_in[5];
    const float* evals = (const float*)d_in[6];
    float* out = (float*)d_out;

    char* ws = (char*)d_ws;
    size_t off = 0;
    auto alloc = [&](size_t bytes) -> void* {
        void* p = ws + off;
        off += (bytes + 255) & ~(size_t)255;
        return p;
    };
    unsigned short* Hb = (unsigned short*)alloc((size_t)2 * N_NODES * 256 * 2);   // 102.4 MB
    float* A0       = (float*)alloc((size_t)P_TOTAL * N_HEADS * N_NODES * 4);     // 8 MB
    float* A1       = (float*)alloc((size_t)P_TOTAL * N_HEADS * N_NODES * 4);     // 8 MB
    int*   counts   = (int*)alloc((size_t)P_TOTAL * N_NODES * 4);
    int*   cursor   = (int*)alloc((size_t)P_TOTAL * N_NODES * 4);
    int*   rowstart = (int*)alloc((size_t)P_TOTAL * (N_NODES + 1) * 4);
    int*   blocksum = (int*)alloc((size_t)P_TOTAL * 128 * 4);
    unsigned* cv    = (unsigned*)alloc((size_t)P_TOTAL * NEDGE * 4);              // 64 MB
    (void)ws_size; (void)in_sizes; (void)n_in; (void)out_size;

    const int nb = (N_NODES + 1023) / 1024;

    {
        int zn = P_TOTAL * N_NODES;
        zero_kernel<<<(zn + 1023) / 1024, 1024, 0, stream>>>(counts, zn);
        zero_kernel<<<(zn + 1023) / 1024, 1024, 0, stream>>>(cursor, zn);
    }
    gemm_h<<<dim3((N_NODES + 63) / 64, 4, 2), 256, 0, stream>>>(x, W, att0, att1, Hb, A0, A1);
    hist_kernel<<<dim3(NEDGE / 256, P_TOTAL), 256, 0, stream>>>(erows, counts);
    scan1<<<dim3(nb, P_TOTAL), 1024, 0, stream>>>(counts, rowstart, blocksum);
    scan2<<<P_TOTAL, 128, 0, stream>>>(blocksum, rowstart, nb);
    scan3<<<dim3(nb, P_TOTAL), 1024, 0, stream>>>(rowstart, blocksum);
    scatter_kernel<<<dim3(NEDGE / 256, P_TOTAL), 256, 0, stream>>>(erows, ecols, evals,
                                                                   rowstart, cursor, cv);
    row_pass<<<dim3(N_NODES / 16, 2), 256, 0, stream>>>(Hb, A0, A1, rowstart, cv, out);
}

// Round 2
// 3876.178 us; speedup vs baseline: 1.3326x; 1.0166x over previous
//
#include <hip/hip_runtime.h>
#include <hip/hip_bf16.h>
#include <math.h>

#define N_NODES 100000
#define D_IN 256
#define D_OUT 64
#define N_HEADS 4
#define P_TOTAL 5
#define NEDGE 3200000

__device__ __forceinline__ unsigned short f2bf(float f) {
    unsigned u = __float_as_uint(f);
    unsigned r = (u + 0x7FFFu + ((u >> 16) & 1u)) >> 16;
    return (unsigned short)r;
}

// ---------------------------------------------------------------------------
__global__ void zero_kernel(int* __restrict__ p, int n) {
    int i = blockIdx.x * blockDim.x + threadIdx.x;
    if (i < n) p[i] = 0;
}

// ---------------------------------------------------------------------------
// h = (shrink[m,i] @ x).T  -> Hb bf16 [m][n][256]  (ch = i*64+d, node-major)
// 128 nodes x 64 ch tile, 8x4 per thread (was 64x64 / 4x4): 3 ds_read_b128
// per 32 FMA instead of 2 per 16 -- cuts the LDS-issue bottleneck ~25%.
// Fused epilogue: A0[pi][n] = h . att0[pi], A1 likewise, from fp32 accs.
// blockIdx.y == head i (c0 = i*64), blockIdx.z == m.
// ---------------------------------------------------------------------------
__global__ __launch_bounds__(256)
void gemm_h(const float* __restrict__ x, const float* __restrict__ W,
            const float* __restrict__ att0, const float* __restrict__ att1,
            unsigned short* __restrict__ Hb,
            float* __restrict__ A0, float* __restrict__ A1) {
    const int m  = blockIdx.z;
    const int i  = blockIdx.y;        // head
    const int c0 = i * 64;
    const int n0 = blockIdx.x * 128;
    __shared__ float xs[32][132];
    __shared__ float ws[32][68];
    const int t  = threadIdx.x;
    const int c4 = (t & 15) * 4;
    const int n8 = (t >> 4) * 8;
    float acc[8][4];
#pragma unroll
    for (int a = 0; a < 8; ++a)
#pragma unroll
        for (int b = 0; b < 4; ++b) acc[a][b] = 0.f;

    for (int k0 = 0; k0 < 256; k0 += 32) {
#pragma unroll
        for (int it = 0; it < 16; ++it) {
            int idx = it * 256 + t;
            int kk = idx >> 7;
            int nn = idx & 127;
            int gn = n0 + nn;
            xs[kk][nn] = (gn < N_NODES) ? x[(size_t)(k0 + kk) * N_NODES + gn] : 0.f;
        }
#pragma unroll
        for (int it = 0; it < 8; ++it) {
            int idx = it * 256 + t;
            int cc = idx >> 5;
            int kk = idx & 31;
            ws[kk][cc] = W[((size_t)(m * 256 + c0 + cc)) * 256 + (k0 + kk)];
        }
        __syncthreads();
#pragma unroll
        for (int k = 0; k < 32; ++k) {
            float4 wv  = *(const float4*)&ws[k][c4];
            float4 xv0 = *(const float4*)&xs[k][n8];
            float4 xv1 = *(const float4*)&xs[k][n8 + 4];
            float xa[8] = {xv0.x, xv0.y, xv0.z, xv0.w, xv1.x, xv1.y, xv1.z, xv1.w};
            float wa[4] = {wv.x, wv.y, wv.z, wv.w};
#pragma unroll
            for (int a = 0; a < 8; ++a)
#pragma unroll
                for (int b = 0; b < 4; ++b) acc[a][b] += xa[a] * wa[b];
        }
        __syncthreads();
    }
    // bf16 H writeback
#pragma unroll
    for (int a = 0; a < 8; ++a) {
        int gn = n0 + n8 + a;
        if (gn < N_NODES) {
            ushort4 s4;
            s4.x = f2bf(acc[a][0]); s4.y = f2bf(acc[a][1]);
            s4.z = f2bf(acc[a][2]); s4.w = f2bf(acc[a][3]);
            *(ushort4*)&Hb[((size_t)m * N_NODES + gn) * 256 + c0 + c4] = s4;
        }
    }
    // fused attention scalars (fp32 precision)
    const int p0 = m ? 2 : 0;
    const int np = m ? 3 : 2;
    for (int pk = 0; pk < np; ++pk) {
        const int pi = (p0 + pk) * 4 + i;
        float a0v[4], a1v[4];
#pragma unroll
        for (int b = 0; b < 4; ++b) {
            a0v[b] = att0[pi * 64 + c4 + b];
            a1v[b] = att1[pi * 64 + c4 + b];
        }
#pragma unroll
        for (int a = 0; a < 8; ++a) {
            float s0 = 0.f, s1 = 0.f;
#pragma unroll
            for (int b = 0; b < 4; ++b) {
                s0 += acc[a][b] * a0v[b];
                s1 += acc[a][b] * a1v[b];
            }
#pragma unroll
            for (int off = 1; off < 16; off <<= 1) {
                s0 += __shfl_xor(s0, off);
                s1 += __shfl_xor(s1, off);
            }
            int gn = n0 + n8 + a;
            if ((t & 15) == 0 && gn < N_NODES) {
                A0[(size_t)pi * N_NODES + gn] = s0;
                A1[(size_t)pi * N_NODES + gn] = s1;
            }
        }
    }
}

// ---------------------------------------------------------------------------
// CSR build: histogram -> 3-phase exclusive scan -> scatter packed (c,v) u32
// ---------------------------------------------------------------------------
__global__ __launch_bounds__(256)
void hist_kernel(const int* __restrict__ rows, int* __restrict__ counts) {
    const int p = blockIdx.y;
    const int e = blockIdx.x * 256 + threadIdx.x;
    int r = rows[(size_t)p * NEDGE + e];
    atomicAdd(&counts[p * N_NODES + r], 1);
}

__global__ __launch_bounds__(1024)
void scan1(const int* __restrict__ counts, int* __restrict__ rowstart,
           int* __restrict__ blocksum) {
    __shared__ int sh[1024];
    const int p = blockIdx.y, b = blockIdx.x, t = threadIdx.x;
    const int i = b * 1024 + t;
    int v = (i < N_NODES) ? counts[p * N_NODES + i] : 0;
    sh[t] = v;
    __syncthreads();
    for (int off = 1; off < 1024; off <<= 1) {
        int y = (t >= off) ? sh[t - off] : 0;
        __syncthreads();
        sh[t] += y;
        __syncthreads();
    }
    if (i < N_NODES) rowstart[p * (N_NODES + 1) + i] = sh[t] - v;
    if (t == 1023) blocksum[p * 128 + b] = sh[t];
}

__global__ __launch_bounds__(128)
void scan2(int* __restrict__ blocksum, int* __restrict__ rowstart, int nb) {
    __shared__ int sh[128];
    const int p = blockIdx.x, t = threadIdx.x;
    int v = (t < nb) ? blocksum[p * 128 + t] : 0;
    sh[t] = v;
    __syncthreads();
    for (int off = 1; off < 128; off <<= 1) {
        int y = (t >= off) ? sh[t - off] : 0;
        __syncthreads();
        sh[t] += y;
        __syncthreads();
    }
    blocksum[p * 128 + t] = sh[t] - v;
    if (t == 0) rowstart[p * (N_NODES + 1) + N_NODES] = NEDGE;
}

__global__ __launch_bounds__(1024)
void scan3(int* __restrict__ rowstart, const int* __restrict__ blocksum) {
    const int p = blockIdx.y, b = blockIdx.x, t = threadIdx.x;
    const int i = b * 1024 + t;
    if (i < N_NODES) rowstart[p * (N_NODES + 1) + i] += blocksum[p * 128 + b];
}

__global__ __launch_bounds__(256)
void scatter_kernel(const int* __restrict__ rows, const int* __restrict__ cols,
                    const float* __restrict__ vals, const int* __restrict__ rowstart,
                    int* __restrict__ cursor, unsigned* __restrict__ cv) {
    const int p = blockIdx.y;
    const size_t base = (size_t)p * NEDGE;
    const size_t e = (size_t)blockIdx.x * 256 + threadIdx.x;
    int r = rows[base + e];
    int c = cols[base + e];
    float v = vals[base + e];
    int q = (int)(v * 32768.0f + 0.5f);
    if (q > 32767) q = 32767;
    unsigned cu = ((unsigned)c << 15) | (unsigned)q;
    int pos = rowstart[p * (N_NODES + 1) + r] + atomicAdd(&cursor[p * N_NODES + r], 1);
    cv[base + pos] = cu;
}

// ---------------------------------------------------------------------------
// Main pass: block = 4 waves; EACH WAVE covers the full 256-channel H row
// per edge (lane l gathers the 8B chunk ull[l] -> ch 4l..4l+3, head = l>>4).
// Per-edge scalar work (cv decode, H base) is paid ONCE for all 4 heads:
// readfirstlane pins e0/e1 to SGPRs so cv loads scalarize and c-decode runs
// on the SALU pipe. One lane-varying A0 gather serves all heads; den is
// replicated within each 16-lane head group (no cross-lane reduce needed).
// Main loop is a tail-peeled x4 batch with zero predication.
// Each wave owns 4 rows (block tile = 16 rows); LDS transpose for the
// coalesced [ch][node] output write.
// ---------------------------------------------------------------------------
__global__ __launch_bounds__(256)
void row_pass(const unsigned short* __restrict__ Hb, const float* __restrict__ A0,
              const float* __restrict__ A1, const int* __restrict__ rowstart,
              const unsigned* __restrict__ cv, float* __restrict__ out) {
    const int m  = blockIdx.y;
    const int r0 = blockIdx.x * 16;
    const int w  = threadIdx.x >> 6;   // wave 0..3
    const int l  = threadIdx.x & 63;   // lane
    const int head = l >> 4;
    const int hN = head * N_NODES;     // per-lane offset into A0/A1 position plane
    __shared__ float tile[16][260];
    const int p0 = m ? 2 : 0;
    const int np = m ? 3 : 2;
    const unsigned long long* Hm64 =
        (const unsigned long long*)(Hb + (size_t)m * N_NODES * 256);

    for (int rt = 0; rt < 4; ++rt) {
        const int r = r0 + w * 4 + rt;
        float acc0 = 0.f, acc1 = 0.f, acc2 = 0.f, acc3 = 0.f;
        for (int pk = 0; pk < np; ++pk) {
            const int p = p0 + pk;
            const int* rs = rowstart + p * (N_NODES + 1);
            const int e0 = __builtin_amdgcn_readfirstlane(rs[r]);
            const int e1 = __builtin_amdgcn_readfirstlane(rs[r + 1]);
            if (e1 <= e0) continue;
            const float a1r = A1[(size_t)(p * 4) * N_NODES + hN + r];
            const float* A0p = A0 + (size_t)(p * 4) * N_NODES;
            const unsigned* cvp = cv + (size_t)p * NEDGE;
            float den = 0.f;
            float num0 = 0.f, num1 = 0.f, num2 = 0.f, num3 = 0.f;
            int e = e0;
            const int e1m = e0 + ((e1 - e0) & ~3);
            for (; e < e1m; e += 4) {
                unsigned cu0 = cvp[e + 0];
                unsigned cu1 = cvp[e + 1];
                unsigned cu2 = cvp[e + 2];
                unsigned cu3 = cvp[e + 3];
                int c0 = (int)(cu0 >> 15);
                int c1 = (int)(cu1 >> 15);
                int c2 = (int)(cu2 >> 15);
                int c3 = (int)(cu3 >> 15);
                float a00 = A0p[hN + c0];
                float a01 = A0p[hN + c1];
                float a02 = A0p[hN + c2];
                float a03 = A0p[hN + c3];
                const unsigned long long* h0p = Hm64 + (size_t)c0 * 64;
                const unsigned long long* h1p = Hm64 + (size_t)c1 * 64;
                const unsigned long long* h2p = Hm64 + (size_t)c2 * 64;
                const unsigned long long* h3p = Hm64 + (size_t)c3 * 64;
                unsigned long long hv0 = h0p[l];
                unsigned long long hv1 = h1p[l];
                unsigned long long hv2 = h2p[l];
                unsigned long long hv3 = h3p[l];
                float w0 = __expf((float)(cu0 & 32767u) * (1.0f / 32768.0f) * (a00 + a1r));
                float w1 = __expf((float)(cu1 & 32767u) * (1.0f / 32768.0f) * (a01 + a1r));
                float w2 = __expf((float)(cu2 & 32767u) * (1.0f / 32768.0f) * (a02 + a1r));
                float w3 = __expf((float)(cu3 & 32767u) * (1.0f / 32768.0f) * (a03 + a1r));
                den += w0 + w1 + w2 + w3;
                {
                    unsigned lo = (unsigned)hv0, hi = (unsigned)(hv0 >> 32);
                    num0 += w0 * __uint_as_float(lo << 16);
                    num1 += w0 * __uint_as_float(lo & 0xFFFF0000u);
                    num2 += w0 * __uint_as_float(hi << 16);
                    num3 += w0 * __uint_as_float(hi & 0xFFFF0000u);
                }
                {
                    unsigned lo = (unsigned)hv1, hi = (unsigned)(hv1 >> 32);
                    num0 += w1 * __uint_as_float(lo << 16);
                    num1 += w1 * __uint_as_float(lo & 0xFFFF0000u);
                    num2 += w1 * __uint_as_float(hi << 16);
                    num3 += w1 * __uint_as_float(hi & 0xFFFF0000u);
                }
                {
                    unsigned lo = (unsigned)hv2, hi = (unsigned)(hv2 >> 32);
                    num0 += w2 * __uint_as_float(lo << 16);
                    num1 += w2 * __uint_as_float(lo & 0xFFFF0000u);
                    num2 += w2 * __uint_as_float(hi << 16);
                    num3 += w2 * __uint_as_float(hi & 0xFFFF0000u);
                }
                {
                    unsigned lo = (unsigned)hv3, hi = (unsigned)(hv3 >> 32);
                    num0 += w3 * __uint_as_float(lo << 16);
                    num1 += w3 * __uint_as_float(lo & 0xFFFF0000u);
                    num2 += w3 * __uint_as_float(hi << 16);
                    num3 += w3 * __uint_as_float(hi & 0xFFFF0000u);
                }
            }
            for (; e < e1; ++e) {           // tail (<=3 edges)
                unsigned cu = cvp[e];
                int c = (int)(cu >> 15);
                float a0v = A0p[hN + c];
                const unsigned long long* hp = Hm64 + (size_t)c * 64;
                unsigned long long hv = hp[l];
                float wv = __expf((float)(cu & 32767u) * (1.0f / 32768.0f) * (a0v + a1r));
                unsigned lo = (unsigned)hv, hi = (unsigned)(hv >> 32);
                den  += wv;
                num0 += wv * __uint_as_float(lo << 16);
                num1 += wv * __uint_as_float(lo & 0xFFFF0000u);
                num2 += wv * __uint_as_float(hi << 16);
                num3 += wv * __uint_as_float(hi & 0xFFFF0000u);
            }
            float rd = 1.0f / den;
            acc0 += num0 * rd;
            acc1 += num1 * rd;
            acc2 += num2 * rd;
            acc3 += num3 * rd;
        }
        acc0 = acc0 > 0.f ? acc0 : __expf(acc0) - 1.f;  // ELU
        acc1 = acc1 > 0.f ? acc1 : __expf(acc1) - 1.f;
        acc2 = acc2 > 0.f ? acc2 : __expf(acc2) - 1.f;
        acc3 = acc3 > 0.f ? acc3 : __expf(acc3) - 1.f;
        *(float4*)&tile[w * 4 + rt][l * 4] = make_float4(acc0, acc1, acc2, acc3);
    }
    __syncthreads();
    {
        const int ch = threadIdx.x;
        float* dst = out + ((size_t)m * 256 + ch) * N_NODES + r0;
#pragma unroll
        for (int q = 0; q < 4; ++q) {
            float4 v4 = make_float4(tile[q * 4 + 0][ch], tile[q * 4 + 1][ch],
                                    tile[q * 4 + 2][ch], tile[q * 4 + 3][ch]);
            *(float4*)(dst + q * 4) = v4;
        }
    }
}

// ---------------------------------------------------------------------------
extern "C" void kernel_launch(void* const* d_in, const int* in_sizes, int n_in,
                              void* d_out, int out_size, void* d_ws, size_t ws_size,
                              hipStream_t stream) {
    const float* x    = (const float*)d_in[0];
    const float* W    = (const float*)d_in[1];
    const float* att0 = (const float*)d_in[2];
    const float* att1 = (const float*)d_in[3];
    const int*   erows = (const int*)d_in[4];
    const int*   ecols = (const int*)d_in[5];
    const float* evals = (const float*)d_in[6];
    float* out = (float*)d_out;

    char* ws = (char*)d_ws;
    size_t off = 0;
    auto alloc = [&](size_t bytes) -> void* {
        void* p = ws + off;
        off += (bytes + 255) & ~(size_t)255;
        return p;
    };
    unsigned short* Hb = (unsigned short*)alloc((size_t)2 * N_NODES * 256 * 2);   // 102.4 MB
    float* A0       = (float*)alloc((size_t)P_TOTAL * N_HEADS * N_NODES * 4);     // 8 MB
    float* A1       = (float*)alloc((size_t)P_TOTAL * N_HEADS * N_NODES * 4);     // 8 MB
    int*   counts   = (int*)alloc((size_t)P_TOTAL * N_NODES * 4);
    int*   cursor   = (int*)alloc((size_t)P_TOTAL * N_NODES * 4);
    int*   rowstart = (int*)alloc((size_t)P_TOTAL * (N_NODES + 1) * 4);
    int*   blocksum = (int*)alloc((size_t)P_TOTAL * 128 * 4);
    unsigned* cv    = (unsigned*)alloc((size_t)P_TOTAL * NEDGE * 4);              // 64 MB
    (void)ws_size; (void)in_sizes; (void)n_in; (void)out_size;

    const int nb = (N_NODES + 1023) / 1024;

    {
        int zn = P_TOTAL * N_NODES;
        zero_kernel<<<(zn + 1023) / 1024, 1024, 0, stream>>>(counts, zn);
        zero_kernel<<<(zn + 1023) / 1024, 1024, 0, stream>>>(cursor, zn);
    }
    gemm_h<<<dim3((N_NODES + 127) / 128, 4, 2), 256, 0, stream>>>(x, W, att0, att1, Hb, A0, A1);
    hist_kernel<<<dim3(NEDGE / 256, P_TOTAL), 256, 0, stream>>>(erows, counts);
    scan1<<<dim3(nb, P_TOTAL), 1024, 0, stream>>>(counts, rowstart, blocksum);
    scan2<<<P_TOTAL, 128, 0, stream>>>(blocksum, rowstart, nb);
    scan3<<<dim3(nb, P_TOTAL), 1024, 0, stream>>>(rowstart, blocksum);
    scatter_kernel<<<dim3(NEDGE / 256, P_TOTAL), 256, 0, stream>>>(erows, ecols, evals,
                                                                   rowstart, cursor, cv);
    row_pass<<<dim3(N_NODES / 16, 2), 256, 0, stream>>>(Hb, A0, A1, rowstart, cv, out);
}

// Round 3
// 3857.773 us; speedup vs baseline: 1.3389x; 1.0048x over previous
//
#include <hip/hip_runtime.h>
#include <hip/hip_bf16.h>
#include <math.h>

#define N_NODES 100000
#define D_IN 256
#define D_OUT 64
#define N_HEADS 4
#define P_TOTAL 5
#define NEDGE 3200000

__device__ __forceinline__ unsigned short f2bf(float f) {
    unsigned u = __float_as_uint(f);
    unsigned r = (u + 0x7FFFu + ((u >> 16) & 1u)) >> 16;
    return (unsigned short)r;
}

__device__ __forceinline__ float bfLO(unsigned u) { return __uint_as_float(u << 16); }
__device__ __forceinline__ float bfHI(unsigned u) { return __uint_as_float(u & 0xFFFF0000u); }

// ---------------------------------------------------------------------------
__global__ void zero_kernel(int* __restrict__ p, int n) {
    int i = blockIdx.x * blockDim.x + threadIdx.x;
    if (i < n) p[i] = 0;
}

// ---------------------------------------------------------------------------
// h = (shrink[m,i] @ x).T  -> Hb bf16 [m][n][256]  (ch = i*64+d, node-major)
// Fused epilogue: A0[pi][n] = h . att0[pi], A1 likewise, from fp32 accs.
// blockIdx.y == head i (c0 = i*64), blockIdx.z == m.
// ---------------------------------------------------------------------------
__global__ __launch_bounds__(256)
void gemm_h(const float* __restrict__ x, const float* __restrict__ W,
            const float* __restrict__ att0, const float* __restrict__ att1,
            unsigned short* __restrict__ Hb,
            float* __restrict__ A0, float* __restrict__ A1) {
    const int m  = blockIdx.z;
    const int i  = blockIdx.y;        // head
    const int c0 = i * 64;
    const int n0 = blockIdx.x * 128;
    __shared__ float xs[32][132];
    __shared__ float ws[32][68];
    const int t  = threadIdx.x;
    const int c4 = (t & 15) * 4;
    const int n8 = (t >> 4) * 8;
    float acc[8][4];
#pragma unroll
    for (int a = 0; a < 8; ++a)
#pragma unroll
        for (int b = 0; b < 4; ++b) acc[a][b] = 0.f;

    for (int k0 = 0; k0 < 256; k0 += 32) {
#pragma unroll
        for (int it = 0; it < 16; ++it) {
            int idx = it * 256 + t;
            int kk = idx >> 7;
            int nn = idx & 127;
            int gn = n0 + nn;
            xs[kk][nn] = (gn < N_NODES) ? x[(size_t)(k0 + kk) * N_NODES + gn] : 0.f;
        }
#pragma unroll
        for (int it = 0; it < 8; ++it) {
            int idx = it * 256 + t;
            int cc = idx >> 5;
            int kk = idx & 31;
            ws[kk][cc] = W[((size_t)(m * 256 + c0 + cc)) * 256 + (k0 + kk)];
        }
        __syncthreads();
#pragma unroll
        for (int k = 0; k < 32; ++k) {
            float4 wv  = *(const float4*)&ws[k][c4];
            float4 xv0 = *(const float4*)&xs[k][n8];
            float4 xv1 = *(const float4*)&xs[k][n8 + 4];
            float xa[8] = {xv0.x, xv0.y, xv0.z, xv0.w, xv1.x, xv1.y, xv1.z, xv1.w};
            float wa[4] = {wv.x, wv.y, wv.z, wv.w};
#pragma unroll
            for (int a = 0; a < 8; ++a)
#pragma unroll
                for (int b = 0; b < 4; ++b) acc[a][b] += xa[a] * wa[b];
        }
        __syncthreads();
    }
    // bf16 H writeback
#pragma unroll
    for (int a = 0; a < 8; ++a) {
        int gn = n0 + n8 + a;
        if (gn < N_NODES) {
            ushort4 s4;
            s4.x = f2bf(acc[a][0]); s4.y = f2bf(acc[a][1]);
            s4.z = f2bf(acc[a][2]); s4.w = f2bf(acc[a][3]);
            *(ushort4*)&Hb[((size_t)m * N_NODES + gn) * 256 + c0 + c4] = s4;
        }
    }
    // fused attention scalars (fp32 precision)
    const int p0 = m ? 2 : 0;
    const int np = m ? 3 : 2;
    for (int pk = 0; pk < np; ++pk) {
        const int pi = (p0 + pk) * 4 + i;
        float a0v[4], a1v[4];
#pragma unroll
        for (int b = 0; b < 4; ++b) {
            a0v[b] = att0[pi * 64 + c4 + b];
            a1v[b] = att1[pi * 64 + c4 + b];
        }
#pragma unroll
        for (int a = 0; a < 8; ++a) {
            float s0 = 0.f, s1 = 0.f;
#pragma unroll
            for (int b = 0; b < 4; ++b) {
                s0 += acc[a][b] * a0v[b];
                s1 += acc[a][b] * a1v[b];
            }
#pragma unroll
            for (int off = 1; off < 16; off <<= 1) {
                s0 += __shfl_xor(s0, off);
                s1 += __shfl_xor(s1, off);
            }
            int gn = n0 + n8 + a;
            if ((t & 15) == 0 && gn < N_NODES) {
                A0[(size_t)pi * N_NODES + gn] = s0;
                A1[(size_t)pi * N_NODES + gn] = s1;
            }
        }
    }
}

// ---------------------------------------------------------------------------
// CSR build: histogram -> 3-phase exclusive scan -> scatter packed (c,v) u32
// ---------------------------------------------------------------------------
__global__ __launch_bounds__(256)
void hist_kernel(const int* __restrict__ rows, int* __restrict__ counts) {
    const int p = blockIdx.y;
    const int e = blockIdx.x * 256 + threadIdx.x;
    int r = rows[(size_t)p * NEDGE + e];
    atomicAdd(&counts[p * N_NODES + r], 1);
}

__global__ __launch_bounds__(1024)
void scan1(const int* __restrict__ counts, int* __restrict__ rowstart,
           int* __restrict__ blocksum) {
    __shared__ int sh[1024];
    const int p = blockIdx.y, b = blockIdx.x, t = threadIdx.x;
    const int i = b * 1024 + t;
    int v = (i < N_NODES) ? counts[p * N_NODES + i] : 0;
    sh[t] = v;
    __syncthreads();
    for (int off = 1; off < 1024; off <<= 1) {
        int y = (t >= off) ? sh[t - off] : 0;
        __syncthreads();
        sh[t] += y;
        __syncthreads();
    }
    if (i < N_NODES) rowstart[p * (N_NODES + 1) + i] = sh[t] - v;
    if (t == 1023) blocksum[p * 128 + b] = sh[t];
}

__global__ __launch_bounds__(128)
void scan2(int* __restrict__ blocksum, int* __restrict__ rowstart, int nb) {
    __shared__ int sh[128];
    const int p = blockIdx.x, t = threadIdx.x;
    int v = (t < nb) ? blocksum[p * 128 + t] : 0;
    sh[t] = v;
    __syncthreads();
    for (int off = 1; off < 128; off <<= 1) {
        int y = (t >= off) ? sh[t - off] : 0;
        __syncthreads();
        sh[t] += y;
        __syncthreads();
    }
    blocksum[p * 128 + t] = sh[t] - v;
    if (t == 0) rowstart[p * (N_NODES + 1) + N_NODES] = NEDGE;
}

__global__ __launch_bounds__(1024)
void scan3(int* __restrict__ rowstart, const int* __restrict__ blocksum) {
    const int p = blockIdx.y, b = blockIdx.x, t = threadIdx.x;
    const int i = b * 1024 + t;
    if (i < N_NODES) rowstart[p * (N_NODES + 1) + i] += blocksum[p * 128 + b];
}

__global__ __launch_bounds__(256)
void scatter_kernel(const int* __restrict__ rows, const int* __restrict__ cols,
                    const float* __restrict__ vals, const int* __restrict__ rowstart,
                    int* __restrict__ cursor, unsigned* __restrict__ cv) {
    const int p = blockIdx.y;
    const size_t base = (size_t)p * NEDGE;
    const size_t e = (size_t)blockIdx.x * 256 + threadIdx.x;
    int r = rows[base + e];
    int c = cols[base + e];
    float v = vals[base + e];
    int q = (int)(v * 32768.0f + 0.5f);
    if (q > 32767) q = 32767;
    unsigned cu = ((unsigned)c << 15) | (unsigned)q;
    int pos = rowstart[p * (N_NODES + 1) + r] + atomicAdd(&cursor[p * N_NODES + r], 1);
    cv[base + pos] = cu;
}

// ---------------------------------------------------------------------------
// Main pass v3: block = 4 waves, each wave owns 4 rows. Within a wave, each
// 32-lane HALF owns one edge; lane q (0..31) covers 8 channels via ONE uint4
// (16B) gather of the H row. Per edge-pair: 1 H-load instr (1 KB in flight),
// 1 A0 gather, 1 exp -- VMEM instr count and exp cost per edge are halved
// vs v2, and an 8-edge batch keeps ~4.5 KB of loads in flight per wave
// (2x the MLP depth). cv reads are wave-uniform s_loads (SALU decode);
// per-half edge select is one cndmask. Halves are combined with 9
// shfl_xor(32) per (row,position). head = q>>3 (8 ch per lane).
// ---------------------------------------------------------------------------
__global__ __launch_bounds__(256)
void row_pass(const unsigned short* __restrict__ Hb, const float* __restrict__ A0,
              const float* __restrict__ A1, const int* __restrict__ rowstart,
              const unsigned* __restrict__ cv, float* __restrict__ out) {
    const int m    = blockIdx.y;
    const int r0   = blockIdx.x * 16;
    const int w    = threadIdx.x >> 6;   // wave 0..3
    const int l    = threadIdx.x & 63;   // lane
    const int half = l >> 5;
    const int q    = l & 31;             // lane-in-half
    const int head = q >> 3;             // 8 ch per lane -> 8 lanes per head
    const int hN   = head * N_NODES;
    const int ch0  = q * 8;
    __shared__ float tile[16][260];
    const int p0 = m ? 2 : 0;
    const int np = m ? 3 : 2;
    const uint4* Hm4 = (const uint4*)(Hb + (size_t)m * N_NODES * 256);  // 32 uint4 per row

    for (int rt = 0; rt < 4; ++rt) {
        const int r = r0 + w * 4 + rt;
        float acc0 = 0.f, acc1 = 0.f, acc2 = 0.f, acc3 = 0.f;
        float acc4 = 0.f, acc5 = 0.f, acc6 = 0.f, acc7 = 0.f;
        for (int pk = 0; pk < np; ++pk) {
            const int p = p0 + pk;
            const int* rs = rowstart + p * (N_NODES + 1);
            const int e0 = __builtin_amdgcn_readfirstlane(rs[r]);
            const int e1 = __builtin_amdgcn_readfirstlane(rs[r + 1]);
            if (e1 <= e0) continue;
            const float a1r = A1[(size_t)(p * 4) * N_NODES + hN + r];
            const float* A0p = A0 + (size_t)(p * 4) * N_NODES;
            const unsigned* cvp = cv + (size_t)p * NEDGE;
            float den = 0.f;
            float num0 = 0.f, num1 = 0.f, num2 = 0.f, num3 = 0.f;
            float num4 = 0.f, num5 = 0.f, num6 = 0.f, num7 = 0.f;
            int e = e0;

#define ACC8(WK, H4)                                   \
    do {                                               \
        num0 += (WK) * bfLO((H4).x);                   \
        num1 += (WK) * bfHI((H4).x);                   \
        num2 += (WK) * bfLO((H4).y);                   \
        num3 += (WK) * bfHI((H4).y);                   \
        num4 += (WK) * bfLO((H4).z);                   \
        num5 += (WK) * bfHI((H4).z);                   \
        num6 += (WK) * bfLO((H4).w);                   \
        num7 += (WK) * bfHI((H4).w);                   \
    } while (0)

            // main: 8 edges (4 pairs) per iteration
            for (; e + 8 <= e1; e += 8) {
                unsigned cs0 = cvp[e + 0], cs1 = cvp[e + 1];
                unsigned cs2 = cvp[e + 2], cs3 = cvp[e + 3];
                unsigned cs4 = cvp[e + 4], cs5 = cvp[e + 5];
                unsigned cs6 = cvp[e + 6], cs7 = cvp[e + 7];
                unsigned cua = half ? cs1 : cs0;
                unsigned cub = half ? cs3 : cs2;
                unsigned cuc = half ? cs5 : cs4;
                unsigned cud = half ? cs7 : cs6;
                unsigned ca = cua >> 15, cb = cub >> 15, cc = cuc >> 15, cd = cud >> 15;
                float a0a = A0p[hN + (int)ca];
                float a0b = A0p[hN + (int)cb];
                float a0c = A0p[hN + (int)cc];
                float a0d = A0p[hN + (int)cd];
                uint4 ha = Hm4[(size_t)ca * 32 + q];
                uint4 hb = Hm4[(size_t)cb * 32 + q];
                uint4 hc = Hm4[(size_t)cc * 32 + q];
                uint4 hd = Hm4[(size_t)cd * 32 + q];
                float wa = __expf((float)(cua & 32767u) * (1.0f / 32768.0f) * (a0a + a1r));
                float wb = __expf((float)(cub & 32767u) * (1.0f / 32768.0f) * (a0b + a1r));
                float wc = __expf((float)(cuc & 32767u) * (1.0f / 32768.0f) * (a0c + a1r));
                float wd = __expf((float)(cud & 32767u) * (1.0f / 32768.0f) * (a0d + a1r));
                den += wa + wb + wc + wd;
                ACC8(wa, ha);
                ACC8(wb, hb);
                ACC8(wc, hc);
                ACC8(wd, hd);
            }
            // 4-edge block (2 pairs)
            if (e + 4 <= e1) {
                unsigned cs0 = cvp[e + 0], cs1 = cvp[e + 1];
                unsigned cs2 = cvp[e + 2], cs3 = cvp[e + 3];
                unsigned cua = half ? cs1 : cs0;
                unsigned cub = half ? cs3 : cs2;
                unsigned ca = cua >> 15, cb = cub >> 15;
                float a0a = A0p[hN + (int)ca];
                float a0b = A0p[hN + (int)cb];
                uint4 ha = Hm4[(size_t)ca * 32 + q];
                uint4 hb = Hm4[(size_t)cb * 32 + q];
                float wa = __expf((float)(cua & 32767u) * (1.0f / 32768.0f) * (a0a + a1r));
                float wb = __expf((float)(cub & 32767u) * (1.0f / 32768.0f) * (a0b + a1r));
                den += wa + wb;
                ACC8(wa, ha);
                ACC8(wb, hb);
                e += 4;
            }
            // 2-edge block (1 pair)
            if (e + 2 <= e1) {
                unsigned cs0 = cvp[e + 0], cs1 = cvp[e + 1];
                unsigned cua = half ? cs1 : cs0;
                unsigned ca = cua >> 15;
                float a0a = A0p[hN + (int)ca];
                uint4 ha = Hm4[(size_t)ca * 32 + q];
                float wa = __expf((float)(cua & 32767u) * (1.0f / 32768.0f) * (a0a + a1r));
                den += wa;
                ACC8(wa, ha);
                e += 2;
            }
            // single edge: both halves compute, half 1 masked to zero
            if (e < e1) {
                unsigned cua = cvp[e];
                unsigned ca = cua >> 15;
                float a0a = A0p[hN + (int)ca];
                uint4 ha = Hm4[(size_t)ca * 32 + q];
                float wa = __expf((float)(cua & 32767u) * (1.0f / 32768.0f) * (a0a + a1r));
                wa = half ? 0.f : wa;
                den += wa;
                ACC8(wa, ha);
            }
#undef ACC8
            // combine halves
            den  += __shfl_xor(den, 32);
            num0 += __shfl_xor(num0, 32);
            num1 += __shfl_xor(num1, 32);
            num2 += __shfl_xor(num2, 32);
            num3 += __shfl_xor(num3, 32);
            num4 += __shfl_xor(num4, 32);
            num5 += __shfl_xor(num5, 32);
            num6 += __shfl_xor(num6, 32);
            num7 += __shfl_xor(num7, 32);
            float rd = 1.0f / den;
            acc0 += num0 * rd;
            acc1 += num1 * rd;
            acc2 += num2 * rd;
            acc3 += num3 * rd;
            acc4 += num4 * rd;
            acc5 += num5 * rd;
            acc6 += num6 * rd;
            acc7 += num7 * rd;
        }
        acc0 = acc0 > 0.f ? acc0 : __expf(acc0) - 1.f;  // ELU
        acc1 = acc1 > 0.f ? acc1 : __expf(acc1) - 1.f;
        acc2 = acc2 > 0.f ? acc2 : __expf(acc2) - 1.f;
        acc3 = acc3 > 0.f ? acc3 : __expf(acc3) - 1.f;
        acc4 = acc4 > 0.f ? acc4 : __expf(acc4) - 1.f;
        acc5 = acc5 > 0.f ? acc5 : __expf(acc5) - 1.f;
        acc6 = acc6 > 0.f ? acc6 : __expf(acc6) - 1.f;
        acc7 = acc7 > 0.f ? acc7 : __expf(acc7) - 1.f;
        if (half == 0) {
            *(float4*)&tile[w * 4 + rt][ch0]     = make_float4(acc0, acc1, acc2, acc3);
            *(float4*)&tile[w * 4 + rt][ch0 + 4] = make_float4(acc4, acc5, acc6, acc7);
        }
    }
    __syncthreads();
    {
        const int ch = threadIdx.x;
        float* dst = out + ((size_t)m * 256 + ch) * N_NODES + r0;
#pragma unroll
        for (int t4 = 0; t4 < 4; ++t4) {
            float4 v4 = make_float4(tile[t4 * 4 + 0][ch], tile[t4 * 4 + 1][ch],
                                    tile[t4 * 4 + 2][ch], tile[t4 * 4 + 3][ch]);
            *(float4*)(dst + t4 * 4) = v4;
        }
    }
}

// ---------------------------------------------------------------------------
extern "C" void kernel_launch(void* const* d_in, const int* in_sizes, int n_in,
                              void* d_out, int out_size, void* d_ws, size_t ws_size,
                              hipStream_t stream) {
    const float* x    = (const float*)d_in[0];
    const float* W    = (const float*)d_in[1];
    const float* att0 = (const float*)d_in[2];
    const float* att1 = (const float*)d_in[3];
    const int*   erows = (const int*)d_in[4];
    const int*   ecols = (const int*)d_in[5];
    const float* evals = (const float*)d_in[6];
    float* out = (float*)d_out;

    char* ws = (char*)d_ws;
    size_t off = 0;
    auto alloc = [&](size_t bytes) -> void* {
        void* p = ws + off;
        off += (bytes + 255) & ~(size_t)255;
        return p;
    };
    unsigned short* Hb = (unsigned short*)alloc((size_t)2 * N_NODES * 256 * 2);   // 102.4 MB
    float* A0       = (float*)alloc((size_t)P_TOTAL * N_HEADS * N_NODES * 4);     // 8 MB
    float* A1       = (float*)alloc((size_t)P_TOTAL * N_HEADS * N_NODES * 4);     // 8 MB
    int*   counts   = (int*)alloc((size_t)P_TOTAL * N_NODES * 4);
    int*   cursor   = (int*)alloc((size_t)P_TOTAL * N_NODES * 4);
    int*   rowstart = (int*)alloc((size_t)P_TOTAL * (N_NODES + 1) * 4);
    int*   blocksum = (int*)alloc((size_t)P_TOTAL * 128 * 4);
    unsigned* cv    = (unsigned*)alloc((size_t)P_TOTAL * NEDGE * 4);              // 64 MB
    (void)ws_size; (void)in_sizes; (void)n_in; (void)out_size;

    const int nb = (N_NODES + 1023) / 1024;

    {
        int zn = P_TOTAL * N_NODES;
        zero_kernel<<<(zn + 1023) / 1024, 1024, 0, stream>>>(counts, zn);
        zero_kernel<<<(zn + 1023) / 1024, 1024, 0, stream>>>(cursor, zn);
    }
    gemm_h<<<dim3((N_NODES + 127) / 128, 4, 2), 256, 0, stream>>>(x, W, att0, att1, Hb, A0, A1);
    hist_kernel<<<dim3(NEDGE / 256, P_TOTAL), 256, 0, stream>>>(erows, counts);
    scan1<<<dim3(nb, P_TOTAL), 1024, 0, stream>>>(counts, rowstart, blocksum);
    scan2<<<P_TOTAL, 128, 0, stream>>>(blocksum, rowstart, nb);
    scan3<<<dim3(nb, P_TOTAL), 1024, 0, stream>>>(rowstart, blocksum);
    scatter_kernel<<<dim3(NEDGE / 256, P_TOTAL), 256, 0, stream>>>(erows, ecols, evals,
                                                                   rowstart, cursor, cv);
    row_pass<<<dim3(N_NODES / 16, 2), 256, 0, stream>>>(Hb, A0, A1, rowstart, cv, out);
}